// Round 19
// baseline (133.092 us; speedup 1.0000x reference)
//
#include <hip/hip_runtime.h>
#include <hip/hip_bf16.h>
#include <cstddef>

#define BB 64
#define TT 400
#define EE 128
#define HH 512
#define H4 1024
#define VV 50000
#define NCH 8                                  // ctx T-chunks
#define TCH (TT/NCH)                           // 50
#define LSTR 136                               // fc2 LDS row stride in shorts (128+8 pad)

// ---- d_out layout (floats), reference return order ----
#define OFF_OUT     0
#define OFF_CURHID  (BB*VV)                    // 3,200,000
#define OFF_ATTN    (OFF_CURHID + 2*BB*HH)     // 3,265,536
#define OFF_COPY    (OFF_ATTN + BB*TT)         // 3,291,136
#define OFF_NEWCOV  (OFF_COPY + BB*VV)         // 6,491,136
#define OFF_LOSS    (OFF_NEWCOV + BB*TT)       // 6,516,736

// ---- workspace layout (floats; bf16 buffers noted) ----
#define WS_S      0                            // f32 s 64x512
#define WS_ESC    (WS_S + BB*HH)               // f32 enc·aW0 partial scores 64x400
#define WS_NIB    (WS_ESC + BB*TT)             // bf16 ni 64x1024
#define WS_A1     (WS_NIB + BB*H4/2)           // bf16 [s|ctx] 64x1024
#define WS_AX0    (WS_A1 + BB*H4/2)            // bf16 emb 64x128
#define WS_AH0    (WS_AX0 + BB*EE/2)           // bf16 h_prev0 64x512
#define WS_AH1    (WS_AH0 + BB*HH/2)           // bf16 h_prev1 64x512
#define WS_AX1    (WS_AH1 + BB*HH/2)           // bf16 h0 64x512
#define WS_PGEN   (WS_AX1 + BB*HH/2)
#define WS_RM     (WS_PGEN + 64)
#define WS_RS     (WS_RM + 64)
#define WS_CTXP   (WS_RS + 64)                 // f32 partial ctx 64x8x512 (1 MB)
#define WS_LOGITS (WS_CTXP + BB*NCH*HH)        // bf16 64x50000

typedef __attribute__((ext_vector_type(8))) short short8v;
typedef __attribute__((ext_vector_type(4))) short short4v;
typedef __attribute__((ext_vector_type(4))) float f32x4;

__device__ __forceinline__ float wredsum(float v) {
#pragma unroll
  for (int o = 32; o > 0; o >>= 1) v += __shfl_down(v, o, 64);
  return v;
}
__device__ __forceinline__ float wredmax(float v) {
#pragma unroll
  for (int o = 32; o > 0; o >>= 1) v = fmaxf(v, __shfl_down(v, o, 64));
  return v;
}
__device__ __forceinline__ float dot4(float4 a, float4 b) {
  return a.x*b.x + a.y*b.y + a.z*b.z + a.w*b.w;
}
__device__ __forceinline__ float sigmoidf(float x) { return 1.f / (1.f + expf(-x)); }
__device__ __forceinline__ short bfh(float f) {
  union { __hip_bfloat16 h; short s; } u; u.h = __float2bfloat16(f); return u.s;
}
__device__ __forceinline__ float bf2f(short s) {
  union { unsigned int u; float f; } v; v.u = ((unsigned int)(unsigned short)s) << 16; return v.f;
}

// ---------------- zero copy_prob + loss + rs, bf16 prep, AND esc = enc·aW0 ----------------
__global__ void zero_prep_kernel(float* __restrict__ p, float* __restrict__ loss,
                                 float* __restrict__ rs,
                                 const float* __restrict__ embt, const int* __restrict__ ids,
                                 const float* __restrict__ preh,
                                 const float* __restrict__ enc, const float* __restrict__ aW,
                                 short* __restrict__ ax0, short* __restrict__ ah0,
                                 short* __restrict__ ah1, float* __restrict__ esc) {
  int i = blockIdx.x * 256 + threadIdx.x;   // 800000 float4s
  ((float4*)p)[i] = make_float4(0.f, 0.f, 0.f, 0.f);
  if (i == 0) loss[0] = 0.f;
  if (i < 64) rs[i] = 0.f;
  if (i < BB * EE) {
    int b = i >> 7, k = i & 127;
    ax0[i] = bfh(embt[(size_t)ids[b] * EE + k]);
  } else if (i < BB * EE + 2 * BB * HH) {
    int j = i - BB * EE;
    if (j < BB * HH) ah0[j] = bfh(preh[j]);
    else ah1[j - BB * HH] = bfh(preh[j]);
  }
  // esc[b*TT+t] = enc[b,t,:]·aW[0:512]  (25600 dots over 12500 waves)
  int wgid = blockIdx.x * 4 + (threadIdx.x >> 6);     // 0..12499
  int lane = threadIdx.x & 63;
  int i8 = lane * 8;
  float4 a0 = *(const float4*)&aW[i8];
  float4 a1 = *(const float4*)&aW[i8 + 4];
  for (int idx = wgid; idx < BB * TT; idx += 12500) {
    const float* e = enc + (size_t)idx * HH + i8;
    float d = dot4(*(const float4*)&e[0], a0) + dot4(*(const float4*)&e[4], a1);
    d = wredsum(d);
    if (lane == 0) esc[idx] = d;
  }
}

// ---------------- GRU layer via MFMA, K-split 2 (12 waves/block) ----------------
template<int KX>
__global__ __launch_bounds__(768) void gru_mfma_kernel(
    const short* __restrict__ Ax, const short* __restrict__ Ah,
    const float* __restrict__ W_ih, const float* __restrict__ W_hh,
    const float* __restrict__ b_ih, const float* __restrict__ b_hh,
    const float* __restrict__ hprev,
    float* __restrict__ hout_f, float* __restrict__ hout_o,
    short* __restrict__ hout_b, int bstride) {
  __shared__ float Pf[12 * 256];              // 12 KB partials
  const int w = threadIdx.x >> 6;             // 0..11
  const int lane = threadIdx.x & 63;
  const int r16 = lane & 15, kg = lane >> 4;
  const int j0 = (blockIdx.x & 31) * 16;      // gate-col fragment
  const int bg = blockIdx.x >> 5;             // batch group (16 rows)
  const int half = (w >= 6) ? 1 : 0;          // K-half
  const int wv = w - half * 6;
  const int part = (wv >= 3) ? 1 : 0;         // 0 = ih, 1 = hh
  const int g = wv - part * 3;                // gate r/z/n
  const int K = part ? HH : KX;
  const int Kh = K >> 1;
  const float* Wm = part ? W_hh : W_ih;
  const short* Am = part ? Ah : Ax;

  f32x4 acc = {0.f, 0.f, 0.f, 0.f};
  const float* wp = Wm + (size_t)(g * HH + j0 + r16) * K + half * Kh + kg * 8;
  const short* ap = Am + (size_t)(bg * 16 + r16) * K + half * Kh + kg * 8;
#pragma unroll 4
  for (int k0 = 0; k0 < Kh; k0 += 32) {
    float4 w0 = *(const float4*)(wp + k0);
    float4 w1 = *(const float4*)(wp + k0 + 4);
    short8v a = *(const short8v*)(ap + k0);
    short8v bf;
    bf[0] = bfh(w0.x); bf[1] = bfh(w0.y); bf[2] = bfh(w0.z); bf[3] = bfh(w0.w);
    bf[4] = bfh(w1.x); bf[5] = bfh(w1.y); bf[6] = bfh(w1.z); bf[7] = bfh(w1.w);
    acc = __builtin_amdgcn_mfma_f32_16x16x32_bf16(a, bf, acc, 0, 0, 0);
  }
  float* pw = Pf + (half * 6 + part * 3 + g) * 256;
#pragma unroll
  for (int r = 0; r < 4; r++) pw[(kg * 4 + r) * 16 + r16] = acc[r];
  __syncthreads();
  if (w == 0) {
    int col = j0 + r16;
    float bir = b_ih[col] + b_hh[col];
    float biz = b_ih[HH + col] + b_hh[HH + col];
    float bin = b_ih[2 * HH + col], bhn = b_hh[2 * HH + col];
#pragma unroll
    for (int r = 0; r < 4; r++) {
      int m = kg * 4 + r;
      int row = bg * 16 + m;
      int o = m * 16 + r16;
      float ih_r = Pf[0 * 256 + o] + Pf[6 * 256 + o];
      float ih_z = Pf[1 * 256 + o] + Pf[7 * 256 + o];
      float ih_n = Pf[2 * 256 + o] + Pf[8 * 256 + o];
      float hh_r = Pf[3 * 256 + o] + Pf[9 * 256 + o];
      float hh_z = Pf[4 * 256 + o] + Pf[10 * 256 + o];
      float hh_n = Pf[5 * 256 + o] + Pf[11 * 256 + o];
      float rv = sigmoidf(ih_r + hh_r + bir);
      float zv = sigmoidf(ih_z + hh_z + biz);
      float nv = tanhf(ih_n + bin + rv * (hh_n + bhn));
      float h = (1.f - zv) * nv + zv * hprev[(size_t)row * HH + col];
      hout_f[(size_t)row * HH + col] = h;
      hout_o[(size_t)row * HH + col] = h;
      hout_b[(size_t)row * bstride + col] = bfh(h);
    }
  }
}

// ---------------- fused attn + ctx partials: grid (b, chunk), 512 threads ----------------
__global__ __launch_bounds__(512) void attn_ctx_kernel(
    const float* __restrict__ esc, const float* __restrict__ cov,
    const int* __restrict__ src, const float* __restrict__ s,
    const float* __restrict__ aW, const float* __restrict__ ab,
    const float* __restrict__ covW, const float* __restrict__ covb,
    const float* __restrict__ enc,
    float* __restrict__ dout, float* __restrict__ outc, float* __restrict__ ctxp) {
  int b = blockIdx.x, c = blockIdx.y;
  int tid = threadIdx.x;
  int lane = tid & 63, wid = tid >> 6;
  __shared__ float as[TT];
  __shared__ float sred[24];
  __shared__ float bval[8];
  {
    float a2 = aW[2 * HH + tid];
    float p1 = s[(size_t)b * HH + tid] * aW[HH + tid];
    float p2 = covW[tid] * a2;
    float p3 = covb[tid] * a2;
    float r1 = wredsum(p1), r2 = wredsum(p2), r3 = wredsum(p3);
    if (lane == 0) { sred[wid] = r1; sred[8 + wid] = r2; sred[16 + wid] = r3; }
    __syncthreads();
    if (wid == 0) {
      float q1 = (lane < 8) ? sred[lane] : 0.f;      q1 = wredsum(q1);
      float q2 = (lane < 8) ? sred[8 + lane] : 0.f;  q2 = wredsum(q2);
      float q3 = (lane < 8) ? sred[16 + lane] : 0.f; q3 = wredsum(q3);
      if (lane == 0) { bval[2] = q1; bval[3] = q2; bval[4] = q3 + ab[0]; }
    }
    __syncthreads();
  }
  float sdot = bval[2], c1 = bval[3], c0 = bval[4];
  float cvt = (tid < TT) ? cov[b * TT + tid] : 0.f;
  float v = (tid < TT) ? tanhf(esc[b * TT + tid] + sdot + cvt * c1 + c0) : -1e30f;
  float wm = wredmax(v);
  if (lane == 0) sred[wid] = wm;
  __syncthreads();
  if (wid == 0) {
    float r = (lane < 8) ? sred[lane] : -1e30f;
    r = wredmax(r);
    if (lane == 0) bval[0] = r;
  }
  __syncthreads();
  float m = bval[0];
  float e = (tid < TT) ? expf(v - m) : 0.f;
  float wsm = wredsum(e);
  __syncthreads();
  if (lane == 0) sred[wid] = wsm;
  __syncthreads();
  if (wid == 0) {
    float r = (lane < 8) ? sred[lane] : 0.f;
    r = wredsum(r);
    if (lane == 0) bval[1] = r;
  }
  __syncthreads();
  float denom = bval[1];
  float a = e / denom;
  if (tid < TT) as[tid] = a;
  if (c == 0) {
    float lp = 0.f;
    if (tid < TT) {
      dout[OFF_ATTN + b * TT + tid] = a;
      dout[OFF_NEWCOV + b * TT + tid] = cvt + a;
      lp = fminf(a, cvt);
      atomicAdd(&outc[(size_t)b * VV + src[b * TT + tid]], a);
    }
    float wl = wredsum(lp);
    __syncthreads();
    if (lane == 0) sred[wid] = wl;
    __syncthreads();
    if (wid == 0) {
      float r = (lane < 8) ? sred[lane] : 0.f;
      r = wredsum(r);
      if (lane == 0) atomicAdd(&dout[OFF_LOSS], r);
    }
  }
  __syncthreads();
  const float* ep = enc + ((size_t)b * TT + c * TCH) * HH + tid;
  const float* ac = as + c * TCH;
  float acc = 0.f;
#pragma unroll 10
  for (int t = 0; t < TCH; t++) acc += ac[t] * ep[(size_t)t * HH];
  ctxp[((size_t)b * NCH + c) * HH + tid] = acc;
}

// ---------------- ctx reduce + bf16 into A1 + p_gen ----------------
__global__ void ctxred_pgen_kernel(const float* __restrict__ ctxp, const float* __restrict__ s,
                                   const float* __restrict__ embt, const int* __restrict__ ids,
                                   const float* __restrict__ gW, const float* __restrict__ gb,
                                   short* __restrict__ a1, float* __restrict__ pgen) {
  int b = blockIdx.x, tid = threadIdx.x;     // 512 threads
  int lane = tid & 63, wid = tid >> 6;
  __shared__ float sred[8];
  float acc = 0.f;
#pragma unroll
  for (int c = 0; c < NCH; c++) acc += ctxp[((size_t)b * NCH + c) * HH + tid];
  a1[(size_t)b * H4 + HH + tid] = bfh(acc);
  float part = acc * gW[tid] + s[b * HH + tid] * gW[HH + tid];
  if (tid < EE) part += embt[(size_t)ids[b] * EE + tid] * gW[2 * HH + tid];
  float w = wredsum(part);
  if (lane == 0) sred[wid] = w;
  __syncthreads();
  if (wid == 0) {
    float r = (lane < 8) ? sred[lane] : 0.f;
    r = wredsum(r);
    if (lane == 0) pgen[b] = sigmoidf(r + gb[0]);
  }
}

// ---------------- fc1 via MFMA, K-split 4: ni = tanh(A1 @ W^T + b) -> bf16 ----------------
__global__ __launch_bounds__(256) void fc1_kernel(const short* __restrict__ a1,
                                                  const float* __restrict__ W,
                                                  const float* __restrict__ bias,
                                                  short* __restrict__ nib) {
  __shared__ float part[4096];
  const int w = threadIdx.x >> 6;
  const int lane = threadIdx.x & 63;
  const int r16 = lane & 15, kg = lane >> 4;
  const int v0 = blockIdx.x * 16;
  const int kb = w * 256;

  f32x4 acc0 = {0.f,0.f,0.f,0.f}, acc1 = {0.f,0.f,0.f,0.f};
  f32x4 acc2 = {0.f,0.f,0.f,0.f}, acc3 = {0.f,0.f,0.f,0.f};
  const float* wp = W + (size_t)(v0 + r16) * H4 + kb + kg * 8;
  const short* ap = a1 + (size_t)r16 * H4 + kb + kg * 8;
#pragma unroll 4
  for (int k0 = 0; k0 < 256; k0 += 32) {
    float4 w0 = *(const float4*)(wp + k0);
    float4 w1 = *(const float4*)(wp + k0 + 4);
    short8v a0 = *(const short8v*)(ap + k0);
    short8v a1v = *(const short8v*)(ap + 16 * H4 + k0);
    short8v a2 = *(const short8v*)(ap + 32 * H4 + k0);
    short8v a3 = *(const short8v*)(ap + 48 * H4 + k0);
    short8v bf;
    bf[0] = bfh(w0.x); bf[1] = bfh(w0.y); bf[2] = bfh(w0.z); bf[3] = bfh(w0.w);
    bf[4] = bfh(w1.x); bf[5] = bfh(w1.y); bf[6] = bfh(w1.z); bf[7] = bfh(w1.w);
    acc0 = __builtin_amdgcn_mfma_f32_16x16x32_bf16(a0, bf, acc0, 0, 0, 0);
    acc1 = __builtin_amdgcn_mfma_f32_16x16x32_bf16(a1v, bf, acc1, 0, 0, 0);
    acc2 = __builtin_amdgcn_mfma_f32_16x16x32_bf16(a2, bf, acc2, 0, 0, 0);
    acc3 = __builtin_amdgcn_mfma_f32_16x16x32_bf16(a3, bf, acc3, 0, 0, 0);
  }
  float* pb = part + w * 1024;
#pragma unroll
  for (int r = 0; r < 4; r++) {
    pb[(kg * 4 + r) * 16 + r16]      = acc0[r];
    pb[(16 + kg * 4 + r) * 16 + r16] = acc1[r];
    pb[(32 + kg * 4 + r) * 16 + r16] = acc2[r];
    pb[(48 + kg * 4 + r) * 16 + r16] = acc3[r];
  }
  __syncthreads();
  int idx = threadIdx.x * 4;
  int m = idx >> 4, c0 = idx & 15;
  f32x4 s0 = *(const f32x4*)(part + idx);
  f32x4 s1 = *(const f32x4*)(part + 1024 + idx);
  f32x4 s2 = *(const f32x4*)(part + 2048 + idx);
  f32x4 s3 = *(const f32x4*)(part + 3072 + idx);
  f32x4 bv = *(const f32x4*)(bias + v0 + c0);
  f32x4 o = s0 + s1 + s2 + s3 + bv;
#pragma unroll
  for (int j = 0; j < 4; j++)
    nib[(size_t)m * H4 + v0 + c0 + j] = bfh(tanhf(o[j]));
}

// ---------------- fc2 v9: M-split waves (8 waves/block, 2 frags each) for 2x TLP ----------------
// 6250 total waves (~24/CU) vs 3125; BK=128, 2-deep W reg prefetch, A shared by 8 waves.
__global__ __launch_bounds__(512) void fc2_kernel(const short* __restrict__ nib,
                                                  const float* __restrict__ W,
                                                  const float* __restrict__ bias,
                                                  short* __restrict__ logits_bf,
                                                  float* __restrict__ rs) {
  __shared__ short Wl[64 * LSTR];   // 17.4 KB
  __shared__ short Al[64 * LSTR];   // 17.4 KB
  const int tid = threadIdx.x;
  const int w = tid >> 6, lane = tid & 63;
  const int r16 = lane & 15, kg = lane >> 4;
  const int wn = w & 3, wm = w >> 2;          // N-group, M-half
  const int v0 = blockIdx.x * 64;
  const int srow = tid >> 3, oct = tid & 7;   // staging: 8 threads per row
  const int vr = min(v0 + srow, VV - 1);

  f32x4 acc[2];
  acc[0] = (f32x4){0.f, 0.f, 0.f, 0.f};
  acc[1] = (f32x4){0.f, 0.f, 0.f, 0.f};

  const float* wsrc = W + (size_t)vr * H4 + oct * 16;
  const short* asrc = nib + (size_t)srow * H4 + oct * 16;

  float4 wregA[4], wregB[4];                  // 2-deep W prefetch
  short8v areg0, areg1;                       // 1-deep A
#pragma unroll
  for (int j = 0; j < 4; j++) wregA[j] = *(const float4*)(wsrc + j * 4);
#pragma unroll
  for (int j = 0; j < 4; j++) wregB[j] = *(const float4*)(wsrc + 128 + j * 4);
  areg0 = *(const short8v*)(asrc);
  areg1 = *(const short8v*)(asrc + 8);

  auto step = [&](float4 (&wcur)[4], int ks) {
    // ---- write staged registers -> LDS (convert W to bf16) ----
    short* dst = Wl + srow * LSTR + oct * 16;
#pragma unroll
    for (int j = 0; j < 4; j++) {
      float4 f = wcur[j];
      short4v h; h[0] = bfh(f.x); h[1] = bfh(f.y); h[2] = bfh(f.z); h[3] = bfh(f.w);
      *(short4v*)(dst + j * 4) = h;
    }
    short* adst = Al + srow * LSTR + oct * 16;
    *(short8v*)(adst)     = areg0;
    *(short8v*)(adst + 8) = areg1;
    __syncthreads();
    // ---- refill: this buffer with ks+2's W; aregs with ks+1's A ----
    if (ks < 6) {
#pragma unroll
      for (int j = 0; j < 4; j++) wcur[j] = *(const float4*)(wsrc + (ks + 2) * 128 + j * 4);
    }
    if (ks < 7) {
      areg0 = *(const short8v*)(asrc + (ks + 1) * 128);
      areg1 = *(const short8v*)(asrc + (ks + 1) * 128 + 8);
    }
    // ---- compute: 4 sub-k of 32; wave (wn,wm) owns 16 cols x 32 rows ----
#pragma unroll
    for (int s = 0; s < 4; s++) {
      short8v wf = *(const short8v*)(Wl + (wn * 16 + r16) * LSTR + s * 32 + kg * 8);
#pragma unroll
      for (int i = 0; i < 2; i++) {
        short8v af = *(const short8v*)(Al + (wm * 32 + i * 16 + r16) * LSTR + s * 32 + kg * 8);
        acc[i] = __builtin_amdgcn_mfma_f32_16x16x32_bf16(af, wf, acc[i], 0, 0, 0);
      }
    }
    __syncthreads();
  };
#pragma unroll
  for (int it = 0; it < 4; it++) {
    step(wregA, 2 * it);
    step(wregB, 2 * it + 1);
  }

  // ---- epilogue: transpose via LDS, bf16 logits + per-row exp partial sums ----
  float* sc = (float*)Wl;                     // 16 KB scratch
#pragma unroll
  for (int i = 0; i < 2; i++)
#pragma unroll
    for (int r = 0; r < 4; r++)
      sc[(wm * 32 + i * 16 + kg * 4 + r) * 64 + wn * 16 + r16] = acc[i][r];
  __syncthreads();
  int m = tid >> 3, q = tid & 7;
  int colbase = v0 + q * 8;
  float esum = 0.f;
  if (colbase < VV) {                         // VV%8==0 -> whole group valid
    const float* scp = sc + m * 64 + q * 8;
    short8v lo;
#pragma unroll
    for (int j = 0; j < 8; j++) {
      short lb = bfh(scp[j] + bias[colbase + j]);
      lo[j] = lb;
      esum += expf(bf2f(lb));
    }
    *(short8v*)(logits_bf + (size_t)m * VV + colbase) = lo;
  }
  esum += __shfl_down(esum, 4, 8);
  esum += __shfl_down(esum, 2, 8);
  esum += __shfl_down(esum, 1, 8);
  if (q == 0) atomicAdd(&rs[m], esum);
}

// ---------------- final mix: out = exp(l)/rs * p_gen + copy*(1-p_gen) ----------------
__global__ void final_kernel(const short* __restrict__ logits_bf, const float* __restrict__ rs,
                             const float* __restrict__ pgen,
                             const float* __restrict__ copy, float* __restrict__ out) {
  int i = blockIdx.x * 256 + threadIdx.x;     // over 800000 groups of 4
  int b = (i * 4) / VV;
  float p = pgen[b], s = rs[b];
  short4v l = ((const short4v*)logits_bf)[i];
  float4 c = ((const float4*)copy)[i];
  float q = 1.f - p;
  float ps = p / s;
  float4 o;
  o.x = expf(bf2f(l[0])) * ps + c.x * q;
  o.y = expf(bf2f(l[1])) * ps + c.y * q;
  o.z = expf(bf2f(l[2])) * ps + c.z * q;
  o.w = expf(bf2f(l[3])) * ps + c.w * q;
  ((float4*)out)[i] = o;
}

extern "C" void kernel_launch(void* const* d_in, const int* in_sizes, int n_in,
                              void* d_out, int out_size, void* d_ws, size_t ws_size,
                              hipStream_t stream) {
  const int*   ids  = (const int*)d_in[0];
  const float* preh = (const float*)d_in[1];
  const float* enc  = (const float*)d_in[2];
  const int*   src  = (const int*)d_in[3];
  const float* cov  = (const float*)d_in[4];
  const float* embt = (const float*)d_in[5];
  const float* Wih0 = (const float*)d_in[6];
  const float* Whh0 = (const float*)d_in[7];
  const float* bih0 = (const float*)d_in[8];
  const float* bhh0 = (const float*)d_in[9];
  const float* Wih1 = (const float*)d_in[10];
  const float* Whh1 = (const float*)d_in[11];
  const float* bih1 = (const float*)d_in[12];
  const float* bhh1 = (const float*)d_in[13];
  const float* aW   = (const float*)d_in[14];
  const float* ab   = (const float*)d_in[15];
  const float* covW = (const float*)d_in[16];
  const float* covb = (const float*)d_in[17];
  const float* f1W  = (const float*)d_in[18];
  const float* f1b  = (const float*)d_in[19];
  const float* f2W  = (const float*)d_in[20];
  const float* f2b  = (const float*)d_in[21];
  const float* gW   = (const float*)d_in[22];
  const float* gb   = (const float*)d_in[23];
  float* out = (float*)d_out;
  float* ws  = (float*)d_ws;

  zero_prep_kernel<<<3125, 256, 0, stream>>>(out + OFF_COPY, out + OFF_LOSS, ws + WS_RS,
                                             embt, ids, preh, enc, aW,
                                             (short*)(ws + WS_AX0), (short*)(ws + WS_AH0),
                                             (short*)(ws + WS_AH1), ws + WS_ESC);
  gru_mfma_kernel<EE><<<128, 768, 0, stream>>>(
      (const short*)(ws + WS_AX0), (const short*)(ws + WS_AH0),
      Wih0, Whh0, bih0, bhh0, preh,
      out + OFF_CURHID, out + OFF_CURHID, (short*)(ws + WS_AX1), HH);
  gru_mfma_kernel<HH><<<128, 768, 0, stream>>>(
      (const short*)(ws + WS_AX1), (const short*)(ws + WS_AH1),
      Wih1, Whh1, bih1, bhh1, preh + BB * HH,
      ws + WS_S, out + OFF_CURHID + BB * HH, (short*)(ws + WS_A1), H4);
  attn_ctx_kernel<<<dim3(64, NCH), 512, 0, stream>>>(
      ws + WS_ESC, cov, src, ws + WS_S, aW, ab, covW, covb, enc,
      out, out + OFF_COPY, ws + WS_CTXP);
  ctxred_pgen_kernel<<<64, 512, 0, stream>>>(ws + WS_CTXP, ws + WS_S, embt, ids, gW, gb,
                                             (short*)(ws + WS_A1), ws + WS_PGEN);
  fc1_kernel<<<64, 256, 0, stream>>>((const short*)(ws + WS_A1), f1W, f1b,
                                     (short*)(ws + WS_NIB));
  fc2_kernel<<<782, 512, 0, stream>>>((const short*)(ws + WS_NIB), f2W, f2b,
                                      (short*)(ws + WS_LOGITS), ws + WS_RS);
  final_kernel<<<3125, 256, 0, stream>>>((const short*)(ws + WS_LOGITS), ws + WS_RS,
                                         ws + WS_PGEN, out + OFF_COPY, out);
}

// Round 20
// 120.111 us; speedup vs baseline: 1.1081x; 1.1081x over previous
//
#include <hip/hip_runtime.h>
#include <hip/hip_bf16.h>
#include <cstddef>

#define BB 64
#define TT 400
#define EE 128
#define HH 512
#define H4 1024
#define VV 50000
#define NCH 8                                  // ctx T-chunks
#define TCH (TT/NCH)                           // 50
#define LSTR 136                               // fc2 LDS row stride in shorts (128+8 pad)

// ---- d_out layout (floats), reference return order ----
#define OFF_OUT     0
#define OFF_CURHID  (BB*VV)                    // 3,200,000
#define OFF_ATTN    (OFF_CURHID + 2*BB*HH)     // 3,265,536
#define OFF_COPY    (OFF_ATTN + BB*TT)         // 3,291,136
#define OFF_NEWCOV  (OFF_COPY + BB*VV)         // 6,491,136
#define OFF_LOSS    (OFF_NEWCOV + BB*TT)       // 6,516,736

// ---- workspace layout (floats; bf16 buffers noted) ----
#define WS_S      0                            // f32 s 64x512
#define WS_ESC    (WS_S + BB*HH)               // f32 enc·aW0 partial scores 64x400
#define WS_NIB    (WS_ESC + BB*TT)             // bf16 ni 64x1024
#define WS_A1     (WS_NIB + BB*H4/2)           // bf16 [s|ctx] 64x1024
#define WS_AX0    (WS_A1 + BB*H4/2)            // bf16 emb 64x128
#define WS_AH0    (WS_AX0 + BB*EE/2)           // bf16 h_prev0 64x512
#define WS_AH1    (WS_AH0 + BB*HH/2)           // bf16 h_prev1 64x512
#define WS_AX1    (WS_AH1 + BB*HH/2)           // bf16 h0 64x512
#define WS_PGEN   (WS_AX1 + BB*HH/2)
#define WS_RM     (WS_PGEN + 64)
#define WS_RS     (WS_RM + 64)
#define WS_CTXP   (WS_RS + 64)                 // f32 partial ctx 64x8x512 (1 MB)
#define WS_LOGITS (WS_CTXP + BB*NCH*HH)        // bf16 64x50000

typedef __attribute__((ext_vector_type(8))) short short8v;
typedef __attribute__((ext_vector_type(4))) short short4v;
typedef __attribute__((ext_vector_type(4))) float f32x4;

__device__ __forceinline__ float wredsum(float v) {
#pragma unroll
  for (int o = 32; o > 0; o >>= 1) v += __shfl_down(v, o, 64);
  return v;
}
__device__ __forceinline__ float wredmax(float v) {
#pragma unroll
  for (int o = 32; o > 0; o >>= 1) v = fmaxf(v, __shfl_down(v, o, 64));
  return v;
}
__device__ __forceinline__ float dot4(float4 a, float4 b) {
  return a.x*b.x + a.y*b.y + a.z*b.z + a.w*b.w;
}
__device__ __forceinline__ float sigmoidf(float x) { return 1.f / (1.f + expf(-x)); }
__device__ __forceinline__ short bfh(float f) {
  union { __hip_bfloat16 h; short s; } u; u.h = __float2bfloat16(f); return u.s;
}
__device__ __forceinline__ float bf2f(short s) {
  union { unsigned int u; float f; } v; v.u = ((unsigned int)(unsigned short)s) << 16; return v.f;
}

// ---------------- zero copy_prob + loss + rs, bf16 prep, AND esc = enc·aW0 ----------------
__global__ void zero_prep_kernel(float* __restrict__ p, float* __restrict__ loss,
                                 float* __restrict__ rs,
                                 const float* __restrict__ embt, const int* __restrict__ ids,
                                 const float* __restrict__ preh,
                                 const float* __restrict__ enc, const float* __restrict__ aW,
                                 short* __restrict__ ax0, short* __restrict__ ah0,
                                 short* __restrict__ ah1, float* __restrict__ esc) {
  int i = blockIdx.x * 256 + threadIdx.x;   // 800000 float4s
  ((float4*)p)[i] = make_float4(0.f, 0.f, 0.f, 0.f);
  if (i == 0) loss[0] = 0.f;
  if (i < 64) rs[i] = 0.f;
  if (i < BB * EE) {
    int b = i >> 7, k = i & 127;
    ax0[i] = bfh(embt[(size_t)ids[b] * EE + k]);
  } else if (i < BB * EE + 2 * BB * HH) {
    int j = i - BB * EE;
    if (j < BB * HH) ah0[j] = bfh(preh[j]);
    else ah1[j - BB * HH] = bfh(preh[j]);
  }
  // esc[b*TT+t] = enc[b,t,:]·aW[0:512]  (25600 dots over 12500 waves)
  int wgid = blockIdx.x * 4 + (threadIdx.x >> 6);     // 0..12499
  int lane = threadIdx.x & 63;
  int i8 = lane * 8;
  float4 a0 = *(const float4*)&aW[i8];
  float4 a1 = *(const float4*)&aW[i8 + 4];
  for (int idx = wgid; idx < BB * TT; idx += 12500) {
    const float* e = enc + (size_t)idx * HH + i8;
    float d = dot4(*(const float4*)&e[0], a0) + dot4(*(const float4*)&e[4], a1);
    d = wredsum(d);
    if (lane == 0) esc[idx] = d;
  }
}

// ---------------- GRU layer via MFMA, K-split 2 (12 waves/block) ----------------
template<int KX>
__global__ __launch_bounds__(768) void gru_mfma_kernel(
    const short* __restrict__ Ax, const short* __restrict__ Ah,
    const float* __restrict__ W_ih, const float* __restrict__ W_hh,
    const float* __restrict__ b_ih, const float* __restrict__ b_hh,
    const float* __restrict__ hprev,
    float* __restrict__ hout_f, float* __restrict__ hout_o,
    short* __restrict__ hout_b, int bstride) {
  __shared__ float Pf[12 * 256];              // 12 KB partials
  const int w = threadIdx.x >> 6;             // 0..11
  const int lane = threadIdx.x & 63;
  const int r16 = lane & 15, kg = lane >> 4;
  const int j0 = (blockIdx.x & 31) * 16;      // gate-col fragment
  const int bg = blockIdx.x >> 5;             // batch group (16 rows)
  const int half = (w >= 6) ? 1 : 0;          // K-half
  const int wv = w - half * 6;
  const int part = (wv >= 3) ? 1 : 0;         // 0 = ih, 1 = hh
  const int g = wv - part * 3;                // gate r/z/n
  const int K = part ? HH : KX;
  const int Kh = K >> 1;
  const float* Wm = part ? W_hh : W_ih;
  const short* Am = part ? Ah : Ax;

  f32x4 acc = {0.f, 0.f, 0.f, 0.f};
  const float* wp = Wm + (size_t)(g * HH + j0 + r16) * K + half * Kh + kg * 8;
  const short* ap = Am + (size_t)(bg * 16 + r16) * K + half * Kh + kg * 8;
#pragma unroll 4
  for (int k0 = 0; k0 < Kh; k0 += 32) {
    float4 w0 = *(const float4*)(wp + k0);
    float4 w1 = *(const float4*)(wp + k0 + 4);
    short8v a = *(const short8v*)(ap + k0);
    short8v bf;
    bf[0] = bfh(w0.x); bf[1] = bfh(w0.y); bf[2] = bfh(w0.z); bf[3] = bfh(w0.w);
    bf[4] = bfh(w1.x); bf[5] = bfh(w1.y); bf[6] = bfh(w1.z); bf[7] = bfh(w1.w);
    acc = __builtin_amdgcn_mfma_f32_16x16x32_bf16(a, bf, acc, 0, 0, 0);
  }
  float* pw = Pf + (half * 6 + part * 3 + g) * 256;
#pragma unroll
  for (int r = 0; r < 4; r++) pw[(kg * 4 + r) * 16 + r16] = acc[r];
  __syncthreads();
  if (w == 0) {
    int col = j0 + r16;
    float bir = b_ih[col] + b_hh[col];
    float biz = b_ih[HH + col] + b_hh[HH + col];
    float bin = b_ih[2 * HH + col], bhn = b_hh[2 * HH + col];
#pragma unroll
    for (int r = 0; r < 4; r++) {
      int m = kg * 4 + r;
      int row = bg * 16 + m;
      int o = m * 16 + r16;
      float ih_r = Pf[0 * 256 + o] + Pf[6 * 256 + o];
      float ih_z = Pf[1 * 256 + o] + Pf[7 * 256 + o];
      float ih_n = Pf[2 * 256 + o] + Pf[8 * 256 + o];
      float hh_r = Pf[3 * 256 + o] + Pf[9 * 256 + o];
      float hh_z = Pf[4 * 256 + o] + Pf[10 * 256 + o];
      float hh_n = Pf[5 * 256 + o] + Pf[11 * 256 + o];
      float rv = sigmoidf(ih_r + hh_r + bir);
      float zv = sigmoidf(ih_z + hh_z + biz);
      float nv = tanhf(ih_n + bin + rv * (hh_n + bhn));
      float h = (1.f - zv) * nv + zv * hprev[(size_t)row * HH + col];
      hout_f[(size_t)row * HH + col] = h;
      hout_o[(size_t)row * HH + col] = h;
      hout_b[(size_t)row * bstride + col] = bfh(h);
    }
  }
}

// ---------------- fused attn + ctx partials: grid (b, chunk), 512 threads ----------------
__global__ __launch_bounds__(512) void attn_ctx_kernel(
    const float* __restrict__ esc, const float* __restrict__ cov,
    const int* __restrict__ src, const float* __restrict__ s,
    const float* __restrict__ aW, const float* __restrict__ ab,
    const float* __restrict__ covW, const float* __restrict__ covb,
    const float* __restrict__ enc,
    float* __restrict__ dout, float* __restrict__ outc, float* __restrict__ ctxp) {
  int b = blockIdx.x, c = blockIdx.y;
  int tid = threadIdx.x;
  int lane = tid & 63, wid = tid >> 6;
  __shared__ float as[TT];
  __shared__ float sred[24];
  __shared__ float bval[8];
  {
    float a2 = aW[2 * HH + tid];
    float p1 = s[(size_t)b * HH + tid] * aW[HH + tid];
    float p2 = covW[tid] * a2;
    float p3 = covb[tid] * a2;
    float r1 = wredsum(p1), r2 = wredsum(p2), r3 = wredsum(p3);
    if (lane == 0) { sred[wid] = r1; sred[8 + wid] = r2; sred[16 + wid] = r3; }
    __syncthreads();
    if (wid == 0) {
      float q1 = (lane < 8) ? sred[lane] : 0.f;      q1 = wredsum(q1);
      float q2 = (lane < 8) ? sred[8 + lane] : 0.f;  q2 = wredsum(q2);
      float q3 = (lane < 8) ? sred[16 + lane] : 0.f; q3 = wredsum(q3);
      if (lane == 0) { bval[2] = q1; bval[3] = q2; bval[4] = q3 + ab[0]; }
    }
    __syncthreads();
  }
  float sdot = bval[2], c1 = bval[3], c0 = bval[4];
  float cvt = (tid < TT) ? cov[b * TT + tid] : 0.f;
  float v = (tid < TT) ? tanhf(esc[b * TT + tid] + sdot + cvt * c1 + c0) : -1e30f;
  float wm = wredmax(v);
  if (lane == 0) sred[wid] = wm;
  __syncthreads();
  if (wid == 0) {
    float r = (lane < 8) ? sred[lane] : -1e30f;
    r = wredmax(r);
    if (lane == 0) bval[0] = r;
  }
  __syncthreads();
  float m = bval[0];
  float e = (tid < TT) ? expf(v - m) : 0.f;
  float wsm = wredsum(e);
  __syncthreads();
  if (lane == 0) sred[wid] = wsm;
  __syncthreads();
  if (wid == 0) {
    float r = (lane < 8) ? sred[lane] : 0.f;
    r = wredsum(r);
    if (lane == 0) bval[1] = r;
  }
  __syncthreads();
  float denom = bval[1];
  float a = e / denom;
  if (tid < TT) as[tid] = a;
  if (c == 0) {
    float lp = 0.f;
    if (tid < TT) {
      dout[OFF_ATTN + b * TT + tid] = a;
      dout[OFF_NEWCOV + b * TT + tid] = cvt + a;
      lp = fminf(a, cvt);
      atomicAdd(&outc[(size_t)b * VV + src[b * TT + tid]], a);
    }
    float wl = wredsum(lp);
    __syncthreads();
    if (lane == 0) sred[wid] = wl;
    __syncthreads();
    if (wid == 0) {
      float r = (lane < 8) ? sred[lane] : 0.f;
      r = wredsum(r);
      if (lane == 0) atomicAdd(&dout[OFF_LOSS], r);
    }
  }
  __syncthreads();
  const float* ep = enc + ((size_t)b * TT + c * TCH) * HH + tid;
  const float* ac = as + c * TCH;
  float acc = 0.f;
#pragma unroll 10
  for (int t = 0; t < TCH; t++) acc += ac[t] * ep[(size_t)t * HH];
  ctxp[((size_t)b * NCH + c) * HH + tid] = acc;
}

// ---------------- ctx reduce + bf16 into A1 + p_gen ----------------
__global__ void ctxred_pgen_kernel(const float* __restrict__ ctxp, const float* __restrict__ s,
                                   const float* __restrict__ embt, const int* __restrict__ ids,
                                   const float* __restrict__ gW, const float* __restrict__ gb,
                                   short* __restrict__ a1, float* __restrict__ pgen) {
  int b = blockIdx.x, tid = threadIdx.x;     // 512 threads
  int lane = tid & 63, wid = tid >> 6;
  __shared__ float sred[8];
  float acc = 0.f;
#pragma unroll
  for (int c = 0; c < NCH; c++) acc += ctxp[((size_t)b * NCH + c) * HH + tid];
  a1[(size_t)b * H4 + HH + tid] = bfh(acc);
  float part = acc * gW[tid] + s[b * HH + tid] * gW[HH + tid];
  if (tid < EE) part += embt[(size_t)ids[b] * EE + tid] * gW[2 * HH + tid];
  float w = wredsum(part);
  if (lane == 0) sred[wid] = w;
  __syncthreads();
  if (wid == 0) {
    float r = (lane < 8) ? sred[lane] : 0.f;
    r = wredsum(r);
    if (lane == 0) pgen[b] = sigmoidf(r + gb[0]);
  }
}

// ---------------- fc1 via MFMA, K-split 4: ni = tanh(A1 @ W^T + b) -> bf16 ----------------
__global__ __launch_bounds__(256) void fc1_kernel(const short* __restrict__ a1,
                                                  const float* __restrict__ W,
                                                  const float* __restrict__ bias,
                                                  short* __restrict__ nib) {
  __shared__ float part[4096];
  const int w = threadIdx.x >> 6;
  const int lane = threadIdx.x & 63;
  const int r16 = lane & 15, kg = lane >> 4;
  const int v0 = blockIdx.x * 16;
  const int kb = w * 256;

  f32x4 acc0 = {0.f,0.f,0.f,0.f}, acc1 = {0.f,0.f,0.f,0.f};
  f32x4 acc2 = {0.f,0.f,0.f,0.f}, acc3 = {0.f,0.f,0.f,0.f};
  const float* wp = W + (size_t)(v0 + r16) * H4 + kb + kg * 8;
  const short* ap = a1 + (size_t)r16 * H4 + kb + kg * 8;
#pragma unroll 4
  for (int k0 = 0; k0 < 256; k0 += 32) {
    float4 w0 = *(const float4*)(wp + k0);
    float4 w1 = *(const float4*)(wp + k0 + 4);
    short8v a0 = *(const short8v*)(ap + k0);
    short8v a1v = *(const short8v*)(ap + 16 * H4 + k0);
    short8v a2 = *(const short8v*)(ap + 32 * H4 + k0);
    short8v a3 = *(const short8v*)(ap + 48 * H4 + k0);
    short8v bf;
    bf[0] = bfh(w0.x); bf[1] = bfh(w0.y); bf[2] = bfh(w0.z); bf[3] = bfh(w0.w);
    bf[4] = bfh(w1.x); bf[5] = bfh(w1.y); bf[6] = bfh(w1.z); bf[7] = bfh(w1.w);
    acc0 = __builtin_amdgcn_mfma_f32_16x16x32_bf16(a0, bf, acc0, 0, 0, 0);
    acc1 = __builtin_amdgcn_mfma_f32_16x16x32_bf16(a1v, bf, acc1, 0, 0, 0);
    acc2 = __builtin_amdgcn_mfma_f32_16x16x32_bf16(a2, bf, acc2, 0, 0, 0);
    acc3 = __builtin_amdgcn_mfma_f32_16x16x32_bf16(a3, bf, acc3, 0, 0, 0);
  }
  float* pb = part + w * 1024;
#pragma unroll
  for (int r = 0; r < 4; r++) {
    pb[(kg * 4 + r) * 16 + r16]      = acc0[r];
    pb[(16 + kg * 4 + r) * 16 + r16] = acc1[r];
    pb[(32 + kg * 4 + r) * 16 + r16] = acc2[r];
    pb[(48 + kg * 4 + r) * 16 + r16] = acc3[r];
  }
  __syncthreads();
  int idx = threadIdx.x * 4;
  int m = idx >> 4, c0 = idx & 15;
  f32x4 s0 = *(const f32x4*)(part + idx);
  f32x4 s1 = *(const f32x4*)(part + 1024 + idx);
  f32x4 s2 = *(const f32x4*)(part + 2048 + idx);
  f32x4 s3 = *(const f32x4*)(part + 3072 + idx);
  f32x4 bv = *(const f32x4*)(bias + v0 + c0);
  f32x4 o = s0 + s1 + s2 + s3 + bv;
#pragma unroll
  for (int j = 0; j < 4; j++)
    nib[(size_t)m * H4 + v0 + c0 + j] = bfh(tanhf(o[j]));
}

// ---------------- fc2: LDS MFMA GEMM (W 2-deep reg-prefetch, A LDS-staged), ----------------
// ---------------- bf16 logits + fused exp-sum (verified best: R14, 120.2 µs) ----------------
__global__ __launch_bounds__(256) void fc2_kernel(const short* __restrict__ nib,
                                                  const float* __restrict__ W,
                                                  const float* __restrict__ bias,
                                                  short* __restrict__ logits_bf,
                                                  float* __restrict__ rs) {
  __shared__ short Wl[64 * LSTR];   // 17.4 KB
  __shared__ short Al[64 * LSTR];   // 17.4 KB
  const int tid = threadIdx.x;
  const int w = tid >> 6, lane = tid & 63;
  const int r16 = lane & 15, kg = lane >> 4;
  const int v0 = blockIdx.x * 64;
  const int srow = tid >> 2, quad = tid & 3;          // staging role
  const int vr = min(v0 + srow, VV - 1);              // clamp OOB vocab rows

  f32x4 acc[4];
#pragma unroll
  for (int i = 0; i < 4; i++) acc[i] = (f32x4){0.f, 0.f, 0.f, 0.f};

  const float* wsrc = W + (size_t)vr * H4 + quad * 4;
  const short* asrc = nib + (size_t)srow * H4 + quad * 8;

  float4 wregA[8], wregB[8];                          // 2-deep W prefetch
  short8v areg[4];                                    // 1-deep A (L2-hot)
#pragma unroll
  for (int j = 0; j < 8; j++) wregA[j] = *(const float4*)(wsrc + j * 16);
#pragma unroll
  for (int j = 0; j < 8; j++) wregB[j] = *(const float4*)(wsrc + 128 + j * 16);
#pragma unroll
  for (int j = 0; j < 4; j++) areg[j] = *(const short8v*)(asrc + j * 32);

  auto step = [&](float4 (&wcur)[8], int ks) {
    // ---- write staged registers -> LDS (convert W to bf16) ----
    char* dst = (char*)Wl + srow * (LSTR * 2) + quad * 8;
#pragma unroll
    for (int j = 0; j < 8; j++) {
      float4 f = wcur[j];
      short4v h; h[0] = bfh(f.x); h[1] = bfh(f.y); h[2] = bfh(f.z); h[3] = bfh(f.w);
      *(short4v*)(dst + j * 32) = h;
    }
    char* adst = (char*)Al + srow * (LSTR * 2) + quad * 16;
#pragma unroll
    for (int j = 0; j < 4; j++)
      *(short8v*)(adst + j * 64) = areg[j];
    __syncthreads();
    // ---- refill: this buffer with ks+2's W; areg with ks+1's A ----
    if (ks < 6) {
#pragma unroll
      for (int j = 0; j < 8; j++) wcur[j] = *(const float4*)(wsrc + (ks + 2) * 128 + j * 16);
    }
    if (ks < 7) {
#pragma unroll
      for (int j = 0; j < 4; j++) areg[j] = *(const short8v*)(asrc + (ks + 1) * 128 + j * 32);
    }
    // ---- compute: 4 sub-k of 32; wave w owns 16 vocab cols ----
#pragma unroll
    for (int s = 0; s < 4; s++) {
      short8v wf = *(const short8v*)((char*)Wl + (w * 16 + r16) * (LSTR * 2) + s * 64 + kg * 16);
#pragma unroll
      for (int i = 0; i < 4; i++) {
        short8v af = *(const short8v*)((char*)Al + (i * 16 + r16) * (LSTR * 2) + s * 64 + kg * 16);
        acc[i] = __builtin_amdgcn_mfma_f32_16x16x32_bf16(af, wf, acc[i], 0, 0, 0);
      }
    }
    __syncthreads();
  };
#pragma unroll
  for (int it = 0; it < 4; it++) {
    step(wregA, 2 * it);
    step(wregB, 2 * it + 1);
  }

  // ---- epilogue: transpose via LDS, bf16 logits + per-row exp partial sums ----
  float* sc = (float*)Wl;
#pragma unroll
  for (int i = 0; i < 4; i++)
#pragma unroll
    for (int r = 0; r < 4; r++)
      sc[(i * 16 + kg * 4 + r) * 64 + w * 16 + r16] = acc[i][r];
  __syncthreads();
  int m = tid >> 2, q = tid & 3;
  int colbase = v0 + q * 16;
  float esum = 0.f;
  if (colbase < VV) {
    const float* scp = sc + m * 64 + q * 16;
    short8v lo, hi;
#pragma unroll
    for (int j = 0; j < 8; j++) {
      short lb = bfh(scp[j] + bias[colbase + j]);
      lo[j] = lb;
      esum += expf(bf2f(lb));
    }
#pragma unroll
    for (int j = 0; j < 8; j++) {
      short lb = bfh(scp[8 + j] + bias[colbase + 8 + j]);
      hi[j] = lb;
      esum += expf(bf2f(lb));
    }
    *(short8v*)(logits_bf + (size_t)m * VV + colbase)     = lo;
    *(short8v*)(logits_bf + (size_t)m * VV + colbase + 8) = hi;
  }
  esum += __shfl_down(esum, 2, 4);
  esum += __shfl_down(esum, 1, 4);
  if (q == 0) atomicAdd(&rs[m], esum);
}

// ---------------- final mix: out = exp(l)/rs * p_gen + copy*(1-p_gen) ----------------
__global__ void final_kernel(const short* __restrict__ logits_bf, const float* __restrict__ rs,
                             const float* __restrict__ pgen,
                             const float* __restrict__ copy, float* __restrict__ out) {
  int i = blockIdx.x * 256 + threadIdx.x;     // over 800000 groups of 4
  int b = (i * 4) / VV;
  float p = pgen[b], s = rs[b];
  short4v l = ((const short4v*)logits_bf)[i];
  float4 c = ((const float4*)copy)[i];
  float q = 1.f - p;
  float ps = p / s;
  float4 o;
  o.x = expf(bf2f(l[0])) * ps + c.x * q;
  o.y = expf(bf2f(l[1])) * ps + c.y * q;
  o.z = expf(bf2f(l[2])) * ps + c.z * q;
  o.w = expf(bf2f(l[3])) * ps + c.w * q;
  ((float4*)out)[i] = o;
}

extern "C" void kernel_launch(void* const* d_in, const int* in_sizes, int n_in,
                              void* d_out, int out_size, void* d_ws, size_t ws_size,
                              hipStream_t stream) {
  const int*   ids  = (const int*)d_in[0];
  const float* preh = (const float*)d_in[1];
  const float* enc  = (const float*)d_in[2];
  const int*   src  = (const int*)d_in[3];
  const float* cov  = (const float*)d_in[4];
  const float* embt = (const float*)d_in[5];
  const float* Wih0 = (const float*)d_in[6];
  const float* Whh0 = (const float*)d_in[7];
  const float* bih0 = (const float*)d_in[8];
  const float* bhh0 = (const float*)d_in[9];
  const float* Wih1 = (const float*)d_in[10];
  const float* Whh1 = (const float*)d_in[11];
  const float* bih1 = (const float*)d_in[12];
  const float* bhh1 = (const float*)d_in[13];
  const float* aW   = (const float*)d_in[14];
  const float* ab   = (const float*)d_in[15];
  const float* covW = (const float*)d_in[16];
  const float* covb = (const float*)d_in[17];
  const float* f1W  = (const float*)d_in[18];
  const float* f1b  = (const float*)d_in[19];
  const float* f2W  = (const float*)d_in[20];
  const float* f2b  = (const float*)d_in[21];
  const float* gW   = (const float*)d_in[22];
  const float* gb   = (const float*)d_in[23];
  float* out = (float*)d_out;
  float* ws  = (float*)d_ws;

  zero_prep_kernel<<<3125, 256, 0, stream>>>(out + OFF_COPY, out + OFF_LOSS, ws + WS_RS,
                                             embt, ids, preh, enc, aW,
                                             (short*)(ws + WS_AX0), (short*)(ws + WS_AH0),
                                             (short*)(ws + WS_AH1), ws + WS_ESC);
  gru_mfma_kernel<EE><<<128, 768, 0, stream>>>(
      (const short*)(ws + WS_AX0), (const short*)(ws + WS_AH0),
      Wih0, Whh0, bih0, bhh0, preh,
      out + OFF_CURHID, out + OFF_CURHID, (short*)(ws + WS_AX1), HH);
  gru_mfma_kernel<HH><<<128, 768, 0, stream>>>(
      (const short*)(ws + WS_AX1), (const short*)(ws + WS_AH1),
      Wih1, Whh1, bih1, bhh1, preh + BB * HH,
      ws + WS_S, out + OFF_CURHID + BB * HH, (short*)(ws + WS_A1), H4);
  attn_ctx_kernel<<<dim3(64, NCH), 512, 0, stream>>>(
      ws + WS_ESC, cov, src, ws + WS_S, aW, ab, covW, covb, enc,
      out, out + OFF_COPY, ws + WS_CTXP);
  ctxred_pgen_kernel<<<64, 512, 0, stream>>>(ws + WS_CTXP, ws + WS_S, embt, ids, gW, gb,
                                             (short*)(ws + WS_A1), ws + WS_PGEN);
  fc1_kernel<<<64, 256, 0, stream>>>((const short*)(ws + WS_A1), f1W, f1b,
                                     (short*)(ws + WS_NIB));
  fc2_kernel<<<782, 256, 0, stream>>>((const short*)(ws + WS_NIB), f2W, f2b,
                                      (short*)(ws + WS_LOGITS), ws + WS_RS);
  final_kernel<<<3125, 256, 0, stream>>>((const short*)(ws + WS_LOGITS), ws + WS_RS,
                                         ws + WS_PGEN, out + OFF_COPY, out);
}